// Round 5
// baseline (175.710 us; speedup 1.0000x reference)
//
#include <hip/hip_runtime.h>
#include <hip/hip_bf16.h>
#include <cstdint>
#include <cstddef>

typedef float  f32x4  __attribute__((ext_vector_type(4)));
typedef __bf16 bf16x8 __attribute__((ext_vector_type(8)));

#define LOG2E 1.4426950408889634f

static constexpr int GN   = 8192;   // nodes
static constexpr int GIN  = 512;    // in features
static constexpr int GOUT = 256;    // out features

// ---------------- async global->LDS (width 16) ----------------
static __device__ __forceinline__ void gload_lds16(const void* g, void* lds){
  typedef uint32_t __attribute__((address_space(1)))* gp_t;
  typedef uint32_t __attribute__((address_space(3)))* lp_t;
  __builtin_amdgcn_global_load_lds((gp_t)(uintptr_t)g,
                                   (lp_t)(uint32_t)(uintptr_t)lds, 16, 0, 0);
}

// ---------------- prep kernels ----------------
// wal/war = (W @ a_{l,r}) * log2(e)  AND  WT[c][k] = bf16(W[k][c]). 512 blocks x 64.
__global__ void k_wprep(const float* __restrict__ W, const float* __restrict__ al,
                        const float* __restrict__ ar, float* __restrict__ wal,
                        float* __restrict__ war, __bf16* __restrict__ WT){
  int k = blockIdx.x;
  int lane = threadIdx.x;
  float4 wv = ((const float4*)(W + (size_t)k*GOUT))[lane];
  float4 av = ((const float4*)al)[lane];
  float4 bv = ((const float4*)ar)[lane];
  // transpose-write W -> WT (bf16)
  WT[(size_t)(lane*4+0)*GIN + k] = (__bf16)wv.x;
  WT[(size_t)(lane*4+1)*GIN + k] = (__bf16)wv.y;
  WT[(size_t)(lane*4+2)*GIN + k] = (__bf16)wv.z;
  WT[(size_t)(lane*4+3)*GIN + k] = (__bf16)wv.w;
  float sl = wv.x*av.x + wv.y*av.y + wv.z*av.z + wv.w*av.w;
  float sr = wv.x*bv.x + wv.y*bv.y + wv.z*bv.z + wv.w*bv.w;
  #pragma unroll
  for(int o=32;o;o>>=1){ sl += __shfl_down(sl,o,64); sr += __shfl_down(sr,o,64); }
  if(lane==0){ wal[k] = sl*LOG2E; war[k] = sr*LOG2E; }
}

// fused: hb = bf16(h); Wh1/Wh2 fp32 row-dots. 4 rows/block.
__global__ void k_prep_h(const float* __restrict__ h, const float* __restrict__ wal,
                         const float* __restrict__ war, __bf16* __restrict__ hb,
                         float* __restrict__ Wh1, float* __restrict__ Wh2){
  int row = blockIdx.x*4 + (threadIdx.x>>6);
  int lane = threadIdx.x & 63;
  const float4* hp = (const float4*)(h + (size_t)row*GIN);
  float4 v0 = hp[lane*2], v1 = hp[lane*2+1];
  bf16x8 o;
  o[0]=(__bf16)v0.x; o[1]=(__bf16)v0.y; o[2]=(__bf16)v0.z; o[3]=(__bf16)v0.w;
  o[4]=(__bf16)v1.x; o[5]=(__bf16)v1.y; o[6]=(__bf16)v1.z; o[7]=(__bf16)v1.w;
  *(bf16x8*)(hb + (size_t)row*GIN + lane*8) = o;
  float4 a0 = ((const float4*)wal)[lane*2], a1 = ((const float4*)wal)[lane*2+1];
  float4 b0 = ((const float4*)war)[lane*2], b1 = ((const float4*)war)[lane*2+1];
  float sl = v0.x*a0.x+v0.y*a0.y+v0.z*a0.z+v0.w*a0.w
           + v1.x*a1.x+v1.y*a1.y+v1.z*a1.z+v1.w*a1.w;
  float sr = v0.x*b0.x+v0.y*b0.y+v0.z*b0.z+v0.w*b0.w
           + v1.x*b1.x+v1.y*b1.y+v1.z*b1.z+v1.w*b1.w;
  #pragma unroll
  for(int of=32;of;of>>=1){ sl += __shfl_down(sl,of,64); sr += __shfl_down(sr,of,64); }
  if(lane==0){ Wh1[row]=sl; Wh2[row]=sr; }
}

// ---------------- GEMM: WhbT[m][n] = sum_k WT[m][k]*hb[n][k]  (= (h@W)^T, bf16)
__global__ __launch_bounds__(256,1) void k_gemmT(const __bf16* __restrict__ WT,
                                                 const __bf16* __restrict__ hb,
                                                 __bf16* __restrict__ WhbT){
  __shared__ __attribute__((aligned(16))) __bf16 As[2][64*64];
  __shared__ __attribute__((aligned(16))) __bf16 Bs[2][128*64];
  const int tid = threadIdx.x, lane = tid & 63, w = tid >> 6;
  const int mb = blockIdx.x >> 6, nb = blockIdx.x & 63;
  const int m0 = mb*64, n0 = nb*128;

  f32x4 acc[8];
  #pragma unroll
  for(int t=0;t<8;t++) acc[t] = (f32x4){0.f,0.f,0.f,0.f};

  const int lr = lane>>3;
  const int bs_sw = ((lane&7)*16) ^ (lr<<4);

  auto stage = [&](int it, int buf){
    const int k0b = it*128;
    #pragma unroll
    for(int s=0;s<6;s++){
      int u = w + s*4;
      const char* src; char* dst;
      if(u < 8){
        int r8 = u*8;
        src = (const char*)(WT + (size_t)(m0 + r8 + lr)*GIN);
        dst = (char*)&As[buf][0] + r8*128;
      } else {
        int r8 = (u-8)*8;
        src = (const char*)(hb + (size_t)(n0 + r8 + lr)*GIN);
        dst = (char*)&Bs[buf][0] + r8*128;
      }
      gload_lds16(src + k0b + bs_sw, dst);
    }
  };

  auto kstep = [&](int kk, int buf){
    const int ko = kk*64 + (lane>>4)*16;
    const int am = 16*w + (lane&15);
    bf16x8 af = *(const bf16x8*)((const char*)&As[buf][0] + am*128 + (ko ^ ((am&7)<<4)));
    #pragma unroll
    for(int t=0;t<8;t++){
      int n = 16*t + (lane&15);
      bf16x8 bf = *(const bf16x8*)((const char*)&Bs[buf][0] + n*128 + (ko ^ ((n&7)<<4)));
      acc[t] = __builtin_amdgcn_mfma_f32_16x16x32_bf16(af, bf, acc[t], 0, 0, 0);
    }
  };

  stage(0,0);
  asm volatile("s_waitcnt vmcnt(0)" ::: "memory");
  __builtin_amdgcn_s_barrier();
  for(int it=0; it<8; it++){
    int buf = it & 1;
    if(it < 7) stage(it+1, buf^1);
    kstep(0, buf);
    kstep(1, buf);
    asm volatile("s_waitcnt vmcnt(0)" ::: "memory");
    __builtin_amdgcn_s_barrier();
  }

  const int mrow = m0 + 16*w + 4*(lane>>4);
  const int nc0  = n0 + (lane&15);
  #pragma unroll
  for(int t=0;t<8;t++){
    #pragma unroll
    for(int r=0;r<4;r++){
      WhbT[(size_t)(mrow + r)*GN + nc0 + 16*t] = (__bf16)acc[t][r];
    }
  }
}

// ---------------- fused masked-softmax-attention (occupancy rebuild) ----------------
// grid 1024: rg=bid>>3 (128 rowgroups of 64), chunk=bid&7 (1024 cols)
// block 128 thr / 2 waves; wave owns 32 rows (2 MFMA sets), all 256 outcols.
// LDS 32KB (2 x 16KB V double-buffer, 32 j-cols per iter) -> 4 blocks/CU.
// adj: 16 coalesced 2-row x 32-col loads/iter, prefetched 1 iter ahead, ballot-packed.
template<bool PART>
__global__ __launch_bounds__(128,2) void k_attn(const int* __restrict__ adj,
                                                const __bf16* __restrict__ WhbT,
                                                const float* __restrict__ Wh1s,
                                                const float* __restrict__ Wh2s,
                                                float* __restrict__ pv_out,
                                                float* __restrict__ s_out){
  __shared__ __attribute__((aligned(16))) char Vs[2][16384];
  const int tid = threadIdx.x, lane = tid & 63, wv = tid >> 6;
  const int rg = blockIdx.x >> 3, chunk = blockIdx.x & 7;
  const int r0 = rg*64, wrb = r0 + wv*32;
  const int j0 = chunk*1024;
  const int la = lane & 15, kg = lane >> 4, kg8 = kg*8;

  f32x4 acc0[16], acc1[16];
  #pragma unroll
  for(int t=0;t<16;t++){ acc0[t] = (f32x4){0.f,0.f,0.f,0.f}; acc1[t] = (f32x4){0.f,0.f,0.f,0.f}; }
  f32x4 accs0 = (f32x4){0.f,0.f,0.f,0.f};
  f32x4 accs1 = (f32x4){0.f,0.f,0.f,0.f};

  bf16x8 ones;
  #pragma unroll
  for(int j=0;j<8;j++) ones[j] = (__bf16)1.0f;

  const float wh1_0 = Wh1s[wrb + la];        // pre-scaled by log2(e)
  const float wh1_1 = Wh1s[wrb + 16 + la];

  // V stage: linear LDS dest (wave-uniform base + lane*16), inverse-swizzled global src.
  // LDS slot (n,q) holds k-bytes kb = q ^ ((n>>1)&3) of V-row n (n = outcol).
  const size_t vsrc_off = (size_t)(wv*16 + (lane>>2))*(GN*2)
                        + (size_t)(((lane&3) ^ ((lane>>3)&3)) << 4);
  // adj: load l covers rows wrb+2l+(lane>>5), col j0+(lane&31)
  const size_t abase = (size_t)(wrb + (lane>>5))*GN + j0 + (lane&31);

  int ax[16];
  uint64_t bc[16];
  auto adj_load = [&](int it){
    const size_t o = abase + it*32;
    #pragma unroll
    for(int l=0;l<16;l++) ax[l] = adj[o + (size_t)(2*l)*GN];
  };
  auto adj_pack = [&](){
    #pragma unroll
    for(int l=0;l<16;l++) bc[l] = __ballot(ax[l] != 0);
  };

  auto stage = [&](int it, int buf){
    const size_t jt2 = (size_t)(j0 + it*32)*2;
    const char* src0 = (const char*)WhbT + jt2 + vsrc_off;
    char* dst0 = &Vs[buf][0] + wv*1024;
    #pragma unroll
    for(int s=0;s<8;s++){
      gload_lds16(src0 + (size_t)s*32*(GN*2), dst0 + s*2048);
    }
  };

  const unsigned odd = lane & 1;
  const unsigned sel = (lane >> 1) & 7;
  // pick lane's 32-bit row-mask (cols jt..jt+32) from 8 wave-uniform ballots, then byte kg8
  auto pick = [&](int base)->unsigned{
    uint32_t h0 = odd ? (uint32_t)(bc[base+0]>>32) : (uint32_t)bc[base+0];
    uint32_t h1 = odd ? (uint32_t)(bc[base+1]>>32) : (uint32_t)bc[base+1];
    uint32_t h2 = odd ? (uint32_t)(bc[base+2]>>32) : (uint32_t)bc[base+2];
    uint32_t h3 = odd ? (uint32_t)(bc[base+3]>>32) : (uint32_t)bc[base+3];
    uint32_t h4 = odd ? (uint32_t)(bc[base+4]>>32) : (uint32_t)bc[base+4];
    uint32_t h5 = odd ? (uint32_t)(bc[base+5]>>32) : (uint32_t)bc[base+5];
    uint32_t h6 = odd ? (uint32_t)(bc[base+6]>>32) : (uint32_t)bc[base+6];
    uint32_t h7 = odd ? (uint32_t)(bc[base+7]>>32) : (uint32_t)bc[base+7];
    uint32_t u01 = (sel&1)? h1:h0, u23 = (sel&1)? h3:h2;
    uint32_t u45 = (sel&1)? h5:h4, u67 = (sel&1)? h7:h6;
    uint32_t v03 = (sel&2)? u23:u01, v47 = (sel&2)? u67:u45;
    uint32_t m32 = (sel&4)? v47:v03;
    return (m32 >> kg8) & 0xffu;
  };

  auto mkpa = [&](float wh1, unsigned m8, float4 w0, float4 w1) -> bf16x8 {
    bf16x8 pa;
    float y, p;
    y = wh1 + w0.x; y = fmaxf(y, 0.2f*y); p = exp2f(y); pa[0] = (__bf16)((m8    )&1 ? p : 0.f);
    y = wh1 + w0.y; y = fmaxf(y, 0.2f*y); p = exp2f(y); pa[1] = (__bf16)((m8>>1)&1 ? p : 0.f);
    y = wh1 + w0.z; y = fmaxf(y, 0.2f*y); p = exp2f(y); pa[2] = (__bf16)((m8>>2)&1 ? p : 0.f);
    y = wh1 + w0.w; y = fmaxf(y, 0.2f*y); p = exp2f(y); pa[3] = (__bf16)((m8>>3)&1 ? p : 0.f);
    y = wh1 + w1.x; y = fmaxf(y, 0.2f*y); p = exp2f(y); pa[4] = (__bf16)((m8>>4)&1 ? p : 0.f);
    y = wh1 + w1.y; y = fmaxf(y, 0.2f*y); p = exp2f(y); pa[5] = (__bf16)((m8>>5)&1 ? p : 0.f);
    y = wh1 + w1.z; y = fmaxf(y, 0.2f*y); p = exp2f(y); pa[6] = (__bf16)((m8>>6)&1 ? p : 0.f);
    y = wh1 + w1.w; y = fmaxf(y, 0.2f*y); p = exp2f(y); pa[7] = (__bf16)((m8>>7)&1 ? p : 0.f);
    return pa;
  };

  auto kstep = [&](int it, int buf){
    const float* wp = Wh2s + j0 + it*32 + kg8;
    float4 w0 = *(const float4*)wp;
    float4 w1 = *(const float4*)(wp + 4);
    unsigned m8_0 = pick(0);
    unsigned m8_1 = pick(8);
    bf16x8 pa0 = mkpa(wh1_0, m8_0, w0, w1);
    bf16x8 pa1 = mkpa(wh1_1, m8_1, w0, w1);
    // ds addr: row la*64 + swizzle, +1024*t folds into the immediate
    const char* vb = &Vs[buf][0] + la*64 + 16*(kg ^ ((la>>1)&3));
    #pragma unroll
    for(int t=0;t<16;t++){
      bf16x8 bv = *(const bf16x8*)(vb + 1024*t);
      acc0[t] = __builtin_amdgcn_mfma_f32_16x16x32_bf16(pa0, bv, acc0[t], 0, 0, 0);
      acc1[t] = __builtin_amdgcn_mfma_f32_16x16x32_bf16(pa1, bv, acc1[t], 0, 0, 0);
    }
    accs0 = __builtin_amdgcn_mfma_f32_16x16x32_bf16(pa0, ones, accs0, 0, 0, 0);
    accs1 = __builtin_amdgcn_mfma_f32_16x16x32_bf16(pa1, ones, accs1, 0, 0, 0);
  };

  // prologue
  stage(0, 0);
  adj_load(0);
  adj_pack();
  asm volatile("s_waitcnt vmcnt(0)" ::: "memory");
  __builtin_amdgcn_s_barrier();

  for(int it=0; it<32; it++){
    int buf = it & 1;
    if(it < 31){
      stage(it+1, buf^1);      // V prefetch -> LDS (linear dest)
      adj_load(it+1);          // adj prefetch -> regs (coalesced)
    }
    kstep(it, buf);
    if(it < 31) adj_pack();    // ballots after MFMAs (loads had full iter to land)
    asm volatile("s_waitcnt vmcnt(0)" ::: "memory");
    __builtin_amdgcn_s_barrier();
  }

  const int orow0 = wrb + 4*kg;
  const int orow1 = wrb + 16 + 4*kg;
  const int ocol  = la;
  if constexpr (PART){
    float* pv = pv_out + (size_t)chunk*GN*GOUT;
    float* sp = s_out  + (size_t)chunk*GN;
    #pragma unroll
    for(int t=0;t<16;t++){
      #pragma unroll
      for(int r=0;r<4;r++){
        pv[(size_t)(orow0 + r)*GOUT + ocol + 16*t] = acc0[t][r];
        pv[(size_t)(orow1 + r)*GOUT + ocol + 16*t] = acc1[t][r];
      }
    }
    if(ocol == 0){
      #pragma unroll
      for(int r=0;r<4;r++){ sp[orow0 + r] = accs0[r]; sp[orow1 + r] = accs1[r]; }
    }
  } else {
    #pragma unroll
    for(int t=0;t<16;t++){
      #pragma unroll
      for(int r=0;r<4;r++){
        atomicAdd(pv_out + (size_t)(orow0 + r)*GOUT + ocol + 16*t, acc0[t][r]);
        atomicAdd(pv_out + (size_t)(orow1 + r)*GOUT + ocol + 16*t, acc1[t][r]);
      }
    }
    if(ocol == 0){
      #pragma unroll
      for(int r=0;r<4;r++){ atomicAdd(s_out + orow0 + r, accs0[r]); atomicAdd(s_out + orow1 + r, accs1[r]); }
    }
  }
}

// ---------------- epilogues ----------------
static __device__ __forceinline__ float elu1(float x){
  return x > 0.f ? x : (exp2f(x*LOG2E) - 1.f);
}

// PART path: combine 8 partials + normalize + ELU
__global__ void k_reduce(const float* __restrict__ accP, const float* __restrict__ accSp,
                         float* __restrict__ out){
  size_t i = ((size_t)blockIdx.x*256 + threadIdx.x)*4;
  int row = (int)(i >> 8);
  float S = 0.f;
  #pragma unroll
  for(int c=0;c<8;c++) S += accSp[(size_t)c*GN + row];
  float4 s = {0.f,0.f,0.f,0.f};
  #pragma unroll
  for(int c=0;c<8;c++){
    float4 v = *(const float4*)(accP + (size_t)c*GN*GOUT + i);
    s.x += v.x; s.y += v.y; s.z += v.z; s.w += v.w;
  }
  float inv = 1.0f / S;
  float4 o;
  o.x = elu1(s.x*inv); o.y = elu1(s.y*inv); o.z = elu1(s.z*inv); o.w = elu1(s.w*inv);
  *(float4*)(out + i) = o;
}

// atomic path: normalize + ELU
__global__ void k_norm(const float* __restrict__ accPV, const float* __restrict__ accS,
                       float* __restrict__ out){
  size_t i = ((size_t)blockIdx.x*256 + threadIdx.x)*4;
  int row = (int)(i >> 8);
  float inv = 1.0f / accS[row];
  float4 v = *(const float4*)(accPV + i);
  float4 o;
  o.x = elu1(v.x*inv); o.y = elu1(v.y*inv); o.z = elu1(v.z*inv); o.w = elu1(v.w*inv);
  *(float4*)(out + i) = o;
}

// ---------------- launch ----------------
extern "C" void kernel_launch(void* const* d_in, const int* in_sizes, int n_in,
                              void* d_out, int out_size, void* d_ws, size_t ws_size,
                              hipStream_t stream){
  const float* h  = (const float*)d_in[0];
  const int*   adj= (const int*)  d_in[1];
  const float* W  = (const float*)d_in[2];
  const float* al = (const float*)d_in[3];
  const float* ar = (const float*)d_in[4];
  float* out = (float*)d_out;
  char* ws = (char*)d_ws;

  const size_t SZ_ACCP = (size_t)8*GN*GOUT*4;        // 67,108,864
  const size_t NEED_A  = SZ_ACCP + 4194304 + 32768 + 32768 + 262144; // 71,630,848

  if(ws_size >= NEED_A){
    float*  accP  = (float*) (ws);
    __bf16* hb    = (__bf16*)(ws);                       // alias (prep-only)
    __bf16* WT    = (__bf16*)(ws + 8388608);             // alias (prep-only)
    float*  wal   = (float*) (ws + 8650752);             // alias (prep-only)
    float*  war   = (float*) (ws + 8652800);             // alias (prep-only)
    __bf16* WhbT  = (__bf16*)(ws + SZ_ACCP);
    float*  Wh1   = (float*) (ws + SZ_ACCP + 4194304);
    float*  Wh2   = (float*) (ws + SZ_ACCP + 4227072);
    float*  accSp = (float*) (ws + SZ_ACCP + 4259840);

    k_wprep <<<512, 64, 0, stream>>>(W, al, ar, wal, war, WT);
    k_prep_h<<<2048, 256, 0, stream>>>(h, wal, war, hb, Wh1, Wh2);
    k_gemmT <<<256, 256, 0, stream>>>(WT, hb, WhbT);
    k_attn<true><<<1024, 128, 0, stream>>>(adj, WhbT, Wh1, Wh2, accP, accSp);
    k_reduce<<<2048, 256, 0, stream>>>(accP, accSp, out);
  } else {
    float*  accPV = (float*) (ws);                       //  8,388,608
    float*  accS  = (float*) (ws + 8388608);             //     32,768
    __bf16* hb    = (__bf16*)(ws + 8421376);             //  8,388,608
    __bf16* WT    = (__bf16*)(ws + 16809984);            //    262,144
    __bf16* WhbT  = (__bf16*)(ws + 17072128);            //  4,194,304
    float*  wal   = (float*) (ws + 21266432);
    float*  war   = (float*) (ws + 21268480);
    float*  Wh1   = (float*) (ws + 21270528);
    float*  Wh2   = (float*) (ws + 21303296);
    if(ws_size < 21336064) return;

    hipMemsetAsync(accPV, 0, 8388608 + 32768, stream);
    k_wprep <<<512, 64, 0, stream>>>(W, al, ar, wal, war, WT);
    k_prep_h<<<2048, 256, 0, stream>>>(h, wal, war, hb, Wh1, Wh2);
    k_gemmT <<<256, 256, 0, stream>>>(WT, hb, WhbT);
    k_attn<false><<<1024, 128, 0, stream>>>(adj, WhbT, Wh1, Wh2, accPV, accS);
    k_norm  <<<2048, 256, 0, stream>>>(accPV, accS, out);
  }
}

// Round 6
// 139.483 us; speedup vs baseline: 1.2597x; 1.2597x over previous
//
#include <hip/hip_runtime.h>
#include <hip/hip_bf16.h>
#include <cstdint>
#include <cstddef>

typedef float  f32x4  __attribute__((ext_vector_type(4)));
typedef __bf16 bf16x8 __attribute__((ext_vector_type(8)));

#define LOG2E 1.4426950408889634f

static constexpr int GN   = 8192;   // nodes
static constexpr int GIN  = 512;    // in features
static constexpr int GOUT = 256;    // out features

// ---------------- async global->LDS (width 16) ----------------
static __device__ __forceinline__ void gload_lds16(const void* g, void* lds){
  typedef uint32_t __attribute__((address_space(1)))* gp_t;
  typedef uint32_t __attribute__((address_space(3)))* lp_t;
  __builtin_amdgcn_global_load_lds((gp_t)(uintptr_t)g,
                                   (lp_t)(uint32_t)(uintptr_t)lds, 16, 0, 0);
}

// ---------------- prep kernels ----------------
// wal/war = (W @ a_{l,r}) * log2(e)  AND  WT[c][k] = bf16(W[k][c]). 512 blocks x 64.
__global__ void k_wprep(const float* __restrict__ W, const float* __restrict__ al,
                        const float* __restrict__ ar, float* __restrict__ wal,
                        float* __restrict__ war, __bf16* __restrict__ WT){
  int k = blockIdx.x;
  int lane = threadIdx.x;
  float4 wv = ((const float4*)(W + (size_t)k*GOUT))[lane];
  float4 av = ((const float4*)al)[lane];
  float4 bv = ((const float4*)ar)[lane];
  WT[(size_t)(lane*4+0)*GIN + k] = (__bf16)wv.x;
  WT[(size_t)(lane*4+1)*GIN + k] = (__bf16)wv.y;
  WT[(size_t)(lane*4+2)*GIN + k] = (__bf16)wv.z;
  WT[(size_t)(lane*4+3)*GIN + k] = (__bf16)wv.w;
  float sl = wv.x*av.x + wv.y*av.y + wv.z*av.z + wv.w*av.w;
  float sr = wv.x*bv.x + wv.y*bv.y + wv.z*bv.z + wv.w*bv.w;
  #pragma unroll
  for(int o=32;o;o>>=1){ sl += __shfl_down(sl,o,64); sr += __shfl_down(sr,o,64); }
  if(lane==0){ wal[k] = sl*LOG2E; war[k] = sr*LOG2E; }
}

// fused: hb = bf16(h); Wh1/Wh2 fp32 row-dots. 4 rows/block.
__global__ void k_prep_h(const float* __restrict__ h, const float* __restrict__ wal,
                         const float* __restrict__ war, __bf16* __restrict__ hb,
                         float* __restrict__ Wh1, float* __restrict__ Wh2){
  int row = blockIdx.x*4 + (threadIdx.x>>6);
  int lane = threadIdx.x & 63;
  const float4* hp = (const float4*)(h + (size_t)row*GIN);
  float4 v0 = hp[lane*2], v1 = hp[lane*2+1];
  bf16x8 o;
  o[0]=(__bf16)v0.x; o[1]=(__bf16)v0.y; o[2]=(__bf16)v0.z; o[3]=(__bf16)v0.w;
  o[4]=(__bf16)v1.x; o[5]=(__bf16)v1.y; o[6]=(__bf16)v1.z; o[7]=(__bf16)v1.w;
  *(bf16x8*)(hb + (size_t)row*GIN + lane*8) = o;
  float4 a0 = ((const float4*)wal)[lane*2], a1 = ((const float4*)wal)[lane*2+1];
  float4 b0 = ((const float4*)war)[lane*2], b1 = ((const float4*)war)[lane*2+1];
  float sl = v0.x*a0.x+v0.y*a0.y+v0.z*a0.z+v0.w*a0.w
           + v1.x*a1.x+v1.y*a1.y+v1.z*a1.z+v1.w*a1.w;
  float sr = v0.x*b0.x+v0.y*b0.y+v0.z*b0.z+v0.w*b0.w
           + v1.x*b1.x+v1.y*b1.y+v1.z*b1.z+v1.w*b1.w;
  #pragma unroll
  for(int of=32;of;of>>=1){ sl += __shfl_down(sl,of,64); sr += __shfl_down(sr,of,64); }
  if(lane==0){ Wh1[row]=sl; Wh2[row]=sr; }
}

// ---------------- GEMM: WhbT[m][n] = sum_k WT[m][k]*hb[n][k]  (= (h@W)^T, bf16)
__global__ __launch_bounds__(256,1) void k_gemmT(const __bf16* __restrict__ WT,
                                                 const __bf16* __restrict__ hb,
                                                 __bf16* __restrict__ WhbT){
  __shared__ __attribute__((aligned(16))) __bf16 As[2][64*64];
  __shared__ __attribute__((aligned(16))) __bf16 Bs[2][128*64];
  const int tid = threadIdx.x, lane = tid & 63, w = tid >> 6;
  const int mb = blockIdx.x >> 6, nb = blockIdx.x & 63;
  const int m0 = mb*64, n0 = nb*128;

  f32x4 acc[8];
  #pragma unroll
  for(int t=0;t<8;t++) acc[t] = (f32x4){0.f,0.f,0.f,0.f};

  const int lr = lane>>3;
  const int bs_sw = ((lane&7)*16) ^ (lr<<4);

  auto stage = [&](int it, int buf){
    const int k0b = it*128;
    #pragma unroll
    for(int s=0;s<6;s++){
      int u = w + s*4;
      const char* src; char* dst;
      if(u < 8){
        int r8 = u*8;
        src = (const char*)(WT + (size_t)(m0 + r8 + lr)*GIN);
        dst = (char*)&As[buf][0] + r8*128;
      } else {
        int r8 = (u-8)*8;
        src = (const char*)(hb + (size_t)(n0 + r8 + lr)*GIN);
        dst = (char*)&Bs[buf][0] + r8*128;
      }
      gload_lds16(src + k0b + bs_sw, dst);
    }
  };

  auto kstep = [&](int kk, int buf){
    const int ko = kk*64 + (lane>>4)*16;
    const int am = 16*w + (lane&15);
    bf16x8 af = *(const bf16x8*)((const char*)&As[buf][0] + am*128 + (ko ^ ((am&7)<<4)));
    #pragma unroll
    for(int t=0;t<8;t++){
      int n = 16*t + (lane&15);
      bf16x8 bf = *(const bf16x8*)((const char*)&Bs[buf][0] + n*128 + (ko ^ ((n&7)<<4)));
      acc[t] = __builtin_amdgcn_mfma_f32_16x16x32_bf16(af, bf, acc[t], 0, 0, 0);
    }
  };

  stage(0,0);
  asm volatile("s_waitcnt vmcnt(0)" ::: "memory");
  __builtin_amdgcn_s_barrier();
  for(int it=0; it<8; it++){
    int buf = it & 1;
    if(it < 7) stage(it+1, buf^1);
    kstep(0, buf);
    kstep(1, buf);
    asm volatile("s_waitcnt vmcnt(0)" ::: "memory");
    __builtin_amdgcn_s_barrier();
  }

  const int mrow = m0 + 16*w + 4*(lane>>4);
  const int nc0  = n0 + (lane&15);
  #pragma unroll
  for(int t=0;t<8;t++){
    #pragma unroll
    for(int r=0;r<4;r++){
      WhbT[(size_t)(mrow + r)*GN + nc0 + 16*t] = (__bf16)acc[t][r];
    }
  }
}

// ---------------- fused masked-softmax-attention (r4 geometry + counted vmcnt) --------
// grid 512: rg=bid>>3 (64 rowgroups of 128), chunk=bid&7 (1024 cols)
// block 256 thr / 4 waves; wave owns rows +0..15 and +64..79 (2 MFMA sets).
// Schedule: per iter issue [stage: 8 gload_lds][adj: 32 reg loads], compute, then
// s_waitcnt vmcnt(32) -> waits ONLY the 8 stage loads; adj loads stay in flight
// across the barrier and are consumed (ballot-packed) at the TOP of the next iter.
template<bool PART>
__global__ __launch_bounds__(256,2) void k_attn(const int* __restrict__ adj,
                                                const __bf16* __restrict__ WhbT,
                                                const float* __restrict__ Wh1s,
                                                const float* __restrict__ Wh2s,
                                                float* __restrict__ pv_out,
                                                float* __restrict__ s_out){
  __shared__ __attribute__((aligned(16))) __bf16 Vs[2][256*64];
  const int tid = threadIdx.x, lane = tid & 63, w = tid >> 6;
  const int rg = blockIdx.x >> 3, chunk = blockIdx.x & 7;
  const int r0 = rg * 128;
  const int j0 = chunk * 1024;

  f32x4 acc0[16], acc1[16];
  #pragma unroll
  for(int t=0;t<16;t++){ acc0[t] = (f32x4){0.f,0.f,0.f,0.f}; acc1[t] = (f32x4){0.f,0.f,0.f,0.f}; }
  f32x4 accs0 = (f32x4){0.f,0.f,0.f,0.f};
  f32x4 accs1 = (f32x4){0.f,0.f,0.f,0.f};

  bf16x8 ones;
  #pragma unroll
  for(int j=0;j<8;j++) ones[j] = (__bf16)1.0f;

  const int kg  = lane >> 4;
  const int kg8 = kg << 3;
  const int myrow0 = r0 + 16*w + (lane & 15);
  const float wh1_0 = Wh1s[myrow0];                 // pre-scaled by log2(e)
  const float wh1_1 = Wh1s[myrow0 + 64];
  const float* wh2p = Wh2s + j0 + kg8;

  const size_t arow0 = (size_t)(r0 + 16*w) * GN + j0;
  const size_t arow1 = arow0 + (size_t)64 * GN;

  const int lr = lane>>3;
  const int bs_sw = ((lane&7)*16) ^ (lr<<4);

  auto stage = [&](int it, int buf){
    const int colb = (j0 + it*64)*2;
    #pragma unroll
    for(int s=0;s<8;s++){
      int u = w + s*4;
      int r8 = u*8;
      const char* src = (const char*)WhbT + (size_t)(r8 + lr)*(GN*2) + colb + bs_sw;
      gload_lds16(src, (char*)&Vs[buf][0] + r8*128);
    }
  };

  int a0p[16], a1p[16];
  auto adj_load = [&](int tt){
    const int co = tt*64 + lane;
    #pragma unroll
    for(int r=0;r<16;r++) a0p[r] = adj[arow0 + (size_t)r*GN + co];
    #pragma unroll
    for(int r=0;r<16;r++) a1p[r] = adj[arow1 + (size_t)r*GN + co];
  };

  uint64_t mk0, mk1;
  auto adj_pack = [&](){
    uint64_t n0 = 0, n1 = 0;
    #pragma unroll
    for(int r=0;r<16;r++){
      uint64_t b = __ballot(a0p[r] != 0);
      if((lane&15)==r) n0 = b;
    }
    #pragma unroll
    for(int r=0;r<16;r++){
      uint64_t b = __ballot(a1p[r] != 0);
      if((lane&15)==r) n1 = b;
    }
    mk0 = n0; mk1 = n1;
  };

  auto mkpa = [&](float wh1, unsigned m8, float4 w0, float4 w1) -> bf16x8 {
    bf16x8 pa;
    float y, p;
    y = wh1 + w0.x; y = fmaxf(y, 0.2f*y); p = exp2f(y); pa[0] = (__bf16)((m8    )&1 ? p : 0.f);
    y = wh1 + w0.y; y = fmaxf(y, 0.2f*y); p = exp2f(y); pa[1] = (__bf16)((m8>>1)&1 ? p : 0.f);
    y = wh1 + w0.z; y = fmaxf(y, 0.2f*y); p = exp2f(y); pa[2] = (__bf16)((m8>>2)&1 ? p : 0.f);
    y = wh1 + w0.w; y = fmaxf(y, 0.2f*y); p = exp2f(y); pa[3] = (__bf16)((m8>>3)&1 ? p : 0.f);
    y = wh1 + w1.x; y = fmaxf(y, 0.2f*y); p = exp2f(y); pa[4] = (__bf16)((m8>>4)&1 ? p : 0.f);
    y = wh1 + w1.y; y = fmaxf(y, 0.2f*y); p = exp2f(y); pa[5] = (__bf16)((m8>>5)&1 ? p : 0.f);
    y = wh1 + w1.z; y = fmaxf(y, 0.2f*y); p = exp2f(y); pa[6] = (__bf16)((m8>>6)&1 ? p : 0.f);
    y = wh1 + w1.w; y = fmaxf(y, 0.2f*y); p = exp2f(y); pa[7] = (__bf16)((m8>>7)&1 ? p : 0.f);
    return pa;
  };

  auto kstep = [&](int it, int kk, int buf){
    const float* wp = wh2p + it*64 + kk*32;
    float4 w0 = *(const float4*)wp;
    float4 w1 = *(const float4*)(wp + 4);
    unsigned m8_0 = (unsigned)((mk0 >> (kk*32 + kg8)) & 0xffULL);
    unsigned m8_1 = (unsigned)((mk1 >> (kk*32 + kg8)) & 0xffULL);
    bf16x8 pa0 = mkpa(wh1_0, m8_0, w0, w1);
    bf16x8 pa1 = mkpa(wh1_1, m8_1, w0, w1);
    const int ko = kk*64 + kg*16;
    #pragma unroll
    for(int t=0;t<16;t++){
      int n = 16*t + (lane&15);
      bf16x8 bv = *(const bf16x8*)((const char*)&Vs[buf][0] + n*128 + (ko ^ ((n&7)<<4)));
      acc0[t] = __builtin_amdgcn_mfma_f32_16x16x32_bf16(pa0, bv, acc0[t], 0, 0, 0);
      acc1[t] = __builtin_amdgcn_mfma_f32_16x16x32_bf16(pa1, bv, acc1[t], 0, 0, 0);
    }
    accs0 = __builtin_amdgcn_mfma_f32_16x16x32_bf16(pa0, ones, accs0, 0, 0, 0);
    accs1 = __builtin_amdgcn_mfma_f32_16x16x32_bf16(pa1, ones, accs1, 0, 0, 0);
  };

  // prologue: V(0) + adj(0) in flight; wait only V (adj waited at first pack)
  stage(0, 0);
  adj_load(0);
  asm volatile("s_waitcnt vmcnt(32)" ::: "memory");
  __builtin_amdgcn_s_barrier();

  for(int it=0; it<16; it++){
    int buf = it & 1;
    adj_pack();                  // ballots on adj(it) (issued last iter; precise backend wait)
    if(it < 15){
      stage(it+1, buf^1);        // 8 gload_lds FIRST (oldest in queue)
      adj_load(it+1);            // 32 adj loads AFTER (stay in flight across barrier)
    }
    kstep(it, 0, buf);
    kstep(it, 1, buf);
    if(it < 15){
      asm volatile("s_waitcnt vmcnt(32)" ::: "memory");   // drains stage only
      __builtin_amdgcn_s_barrier();
    }
  }

  const int orow0 = r0 + 16*w + 4*kg;
  const int orow1 = orow0 + 64;
  const int ocol  = lane & 15;
  if constexpr (PART){
    float* pv = pv_out + (size_t)chunk*GN*GOUT;
    float* sp = s_out  + (size_t)chunk*GN;
    #pragma unroll
    for(int t=0;t<16;t++){
      #pragma unroll
      for(int r=0;r<4;r++){
        pv[(size_t)(orow0 + r)*GOUT + ocol + 16*t] = acc0[t][r];
        pv[(size_t)(orow1 + r)*GOUT + ocol + 16*t] = acc1[t][r];
      }
    }
    if(ocol == 0){
      #pragma unroll
      for(int r=0;r<4;r++){ sp[orow0 + r] = accs0[r]; sp[orow1 + r] = accs1[r]; }
    }
  } else {
    #pragma unroll
    for(int t=0;t<16;t++){
      #pragma unroll
      for(int r=0;r<4;r++){
        atomicAdd(pv_out + (size_t)(orow0 + r)*GOUT + ocol + 16*t, acc0[t][r]);
        atomicAdd(pv_out + (size_t)(orow1 + r)*GOUT + ocol + 16*t, acc1[t][r]);
      }
    }
    if(ocol == 0){
      #pragma unroll
      for(int r=0;r<4;r++){ atomicAdd(s_out + orow0 + r, accs0[r]); atomicAdd(s_out + orow1 + r, accs1[r]); }
    }
  }
}

// ---------------- epilogues ----------------
static __device__ __forceinline__ float elu1(float x){
  return x > 0.f ? x : (exp2f(x*LOG2E) - 1.f);
}

// PART path: combine 8 partials + normalize + ELU
__global__ void k_reduce(const float* __restrict__ accP, const float* __restrict__ accSp,
                         float* __restrict__ out){
  size_t i = ((size_t)blockIdx.x*256 + threadIdx.x)*4;
  int row = (int)(i >> 8);
  float S = 0.f;
  #pragma unroll
  for(int c=0;c<8;c++) S += accSp[(size_t)c*GN + row];
  float4 s = {0.f,0.f,0.f,0.f};
  #pragma unroll
  for(int c=0;c<8;c++){
    float4 v = *(const float4*)(accP + (size_t)c*GN*GOUT + i);
    s.x += v.x; s.y += v.y; s.z += v.z; s.w += v.w;
  }
  float inv = 1.0f / S;
  float4 o;
  o.x = elu1(s.x*inv); o.y = elu1(s.y*inv); o.z = elu1(s.z*inv); o.w = elu1(s.w*inv);
  *(float4*)(out + i) = o;
}

// atomic path: normalize + ELU
__global__ void k_norm(const float* __restrict__ accPV, const float* __restrict__ accS,
                       float* __restrict__ out){
  size_t i = ((size_t)blockIdx.x*256 + threadIdx.x)*4;
  int row = (int)(i >> 8);
  float inv = 1.0f / accS[row];
  float4 v = *(const float4*)(accPV + i);
  float4 o;
  o.x = elu1(v.x*inv); o.y = elu1(v.y*inv); o.z = elu1(v.z*inv); o.w = elu1(v.w*inv);
  *(float4*)(out + i) = o;
}

// ---------------- launch ----------------
extern "C" void kernel_launch(void* const* d_in, const int* in_sizes, int n_in,
                              void* d_out, int out_size, void* d_ws, size_t ws_size,
                              hipStream_t stream){
  const float* h  = (const float*)d_in[0];
  const int*   adj= (const int*)  d_in[1];
  const float* W  = (const float*)d_in[2];
  const float* al = (const float*)d_in[3];
  const float* ar = (const float*)d_in[4];
  float* out = (float*)d_out;
  char* ws = (char*)d_ws;

  const size_t SZ_ACCP = (size_t)8*GN*GOUT*4;        // 67,108,864
  const size_t NEED_A  = SZ_ACCP + 4194304 + 32768 + 32768 + 262144; // 71,630,848

  if(ws_size >= NEED_A){
    float*  accP  = (float*) (ws);
    __bf16* hb    = (__bf16*)(ws);                       // alias (prep-only)
    __bf16* WT    = (__bf16*)(ws + 8388608);             // alias (prep-only)
    float*  wal   = (float*) (ws + 8650752);             // alias (prep-only)
    float*  war   = (float*) (ws + 8652800);             // alias (prep-only)
    __bf16* WhbT  = (__bf16*)(ws + SZ_ACCP);
    float*  Wh1   = (float*) (ws + SZ_ACCP + 4194304);
    float*  Wh2   = (float*) (ws + SZ_ACCP + 4227072);
    float*  accSp = (float*) (ws + SZ_ACCP + 4259840);

    k_wprep <<<512, 64, 0, stream>>>(W, al, ar, wal, war, WT);
    k_prep_h<<<2048, 256, 0, stream>>>(h, wal, war, hb, Wh1, Wh2);
    k_gemmT <<<256, 256, 0, stream>>>(WT, hb, WhbT);
    k_attn<true><<<512, 256, 0, stream>>>(adj, WhbT, Wh1, Wh2, accP, accSp);
    k_reduce<<<2048, 256, 0, stream>>>(accP, accSp, out);
  } else {
    float*  accPV = (float*) (ws);                       //  8,388,608
    float*  accS  = (float*) (ws + 8388608);             //     32,768
    __bf16* hb    = (__bf16*)(ws + 8421376);             //  8,388,608
    __bf16* WT    = (__bf16*)(ws + 16809984);            //    262,144
    __bf16* WhbT  = (__bf16*)(ws + 17072128);            //  4,194,304
    float*  wal   = (float*) (ws + 21266432);
    float*  war   = (float*) (ws + 21268480);
    float*  Wh1   = (float*) (ws + 21270528);
    float*  Wh2   = (float*) (ws + 21303296);
    if(ws_size < 21336064) return;

    hipMemsetAsync(accPV, 0, 8388608 + 32768, stream);
    k_wprep <<<512, 64, 0, stream>>>(W, al, ar, wal, war, WT);
    k_prep_h<<<2048, 256, 0, stream>>>(h, wal, war, hb, Wh1, Wh2);
    k_gemmT <<<256, 256, 0, stream>>>(WT, hb, WhbT);
    k_attn<false><<<512, 256, 0, stream>>>(adj, WhbT, Wh1, Wh2, accPV, accS);
    k_norm  <<<2048, 256, 0, stream>>>(accPV, accS, out);
  }
}